// Round 11
// baseline (477.657 us; speedup 1.0000x reference)
//
#include <hip/hip_runtime.h>
#include <math.h>

#define NB 256      // events
#define KNN 8

typedef __attribute__((ext_vector_type(8))) short short8;
typedef __attribute__((ext_vector_type(4))) float f32x4;

__device__ __forceinline__ float elu_f(float x) {
    return x > 0.f ? x : __expf(x) - 1.f;
}

// round-to-nearest-even fp32 -> bf16 (returns low 16 bits)
__device__ __forceinline__ unsigned bf16rn(float x) {
    unsigned u = __float_as_uint(x);
    return (u + 0x7FFFu + ((u >> 16) & 1u)) >> 16;
}

// split fp32 -> (hi, lo) bf16 pair
__device__ __forceinline__ void bfsplit(float x, short& h, short& l) {
    unsigned hu = bf16rn(x);
    h = (short)hu;
    l = (short)bf16rn(x - __uint_as_float(hu << 16));
}

// ---- sorting-network primitives on u32 keys (validated r1-r10) ------------
__device__ __forceinline__ void cex(unsigned& a, unsigned& b) {
    unsigned lo = min(a, b), hi = max(a, b);
    a = lo; b = hi;
}

__device__ __forceinline__ void sort8(unsigned* s) {
    cex(s[0], s[1]); cex(s[2], s[3]); cex(s[4], s[5]); cex(s[6], s[7]);
    cex(s[0], s[2]); cex(s[1], s[3]); cex(s[4], s[6]); cex(s[5], s[7]);
    cex(s[1], s[2]); cex(s[5], s[6]);
    cex(s[0], s[4]); cex(s[1], s[5]); cex(s[2], s[6]); cex(s[3], s[7]);
    cex(s[2], s[4]); cex(s[3], s[5]);
    cex(s[1], s[2]); cex(s[3], s[4]); cex(s[5], s[6]);
}

__device__ __forceinline__ void merge8(unsigned* v, const unsigned* s) {
#pragma unroll
    for (int i = 0; i < 8; i++) v[i] = min(v[i], s[7 - i]);
    cex(v[0], v[4]); cex(v[1], v[5]); cex(v[2], v[6]); cex(v[3], v[7]);
    cex(v[0], v[2]); cex(v[1], v[3]); cex(v[4], v[6]); cex(v[5], v[7]);
    cex(v[0], v[1]); cex(v[2], v[3]); cex(v[4], v[5]); cex(v[6], v[7]);
}

// ================= MFMA encoder (r6-validated) =============================
template<int FIN, int MODE>
__device__ void encode_mfma_body(const float* __restrict__ x,
    const float* __restrict__ W1, const float* __restrict__ b1,
    const float* __restrict__ W2, const float* __restrict__ b2,
    const float* __restrict__ conv_W, const float* __restrict__ conv_b,
    float* __restrict__ enc, float* __restrict__ e1,
    unsigned short* __restrict__ hiP, unsigned short* __restrict__ loP,
    float* __restrict__ nrmP,
    int blk, float* __restrict__ sx)
{
    int tid = threadIdx.x;
    int lane = tid & 63, wv = tid >> 6;
    int c = lane & 15, kg = lane >> 4;
    size_t node0 = (size_t)blk * 256;

    {
        const float* xb = x + node0 * FIN;
        for (int i = tid; i < 8192; i += 256) {
            int n = i >> 5, f = i & 31;
            sx[i] = (f < FIN) ? xb[n * FIN + f] : 0.f;
        }
    }
    __syncthreads();

    int rb = wv * 64;

#pragma unroll
    for (int ph = 0; ph < 3; ph++) {
        short8 Bh0, Bl0, Bh1, Bl1;
#pragma unroll
        for (int e = 0; e < 8; e++) {
            int kk = kg * 8 + e;
            float w0, w1;
            if (ph == 0) {
                w0 = (kk < FIN) ? W1[kk * 32 + c] : 0.f;
                w1 = (kk < FIN) ? W1[kk * 32 + 16 + c] : 0.f;
            } else if (ph == 1) {
                w0 = W2[kk * 32 + c];
                w1 = W2[kk * 32 + 16 + c];
            } else {
                w0 = conv_W[1024 + kk * 32 + c];
                w1 = conv_W[1024 + kk * 32 + 16 + c];
                if (MODE == 1) {
                    w0 = conv_W[kk * 32 + c] - w0;
                    w1 = conv_W[kk * 32 + 16 + c] - w1;
                }
            }
            short h, l;
            bfsplit(w0, h, l); Bh0[e] = h; Bl0[e] = l;
            bfsplit(w1, h, l); Bh1[e] = h; Bl1[e] = l;
        }
        float bias0, bias1;
        if (ph == 0)      { bias0 = b1[c]; bias1 = b1[16 + c]; }
        else if (ph == 1) { bias0 = b2[c]; bias1 = b2[16 + c]; }
        else              { bias0 = (MODE == 1) ? conv_b[c] : 0.f;
                            bias1 = (MODE == 1) ? conv_b[16 + c] : 0.f; }

#pragma unroll
        for (int t = 0; t < 4; t++) {
            int tb = rb + t * 16;
            int arow = tb + c;
            const float* ap = sx + arow * 32 + kg * 8;
            float4 a0 = *(const float4*)(ap);
            float4 a1 = *(const float4*)(ap + 4);
            float av[8] = {a0.x, a0.y, a0.z, a0.w, a1.x, a1.y, a1.z, a1.w};
            short8 Ah, Al;
#pragma unroll
            for (int e = 0; e < 8; e++) {
                short h, l;
                bfsplit(av[e], h, l);
                Ah[e] = h; Al[e] = l;
            }

            if (MODE == 0 && ph == 2) {
                float nr = 0.f;
#pragma unroll
                for (int e = 0; e < 8; e++) nr = fmaf(av[e], av[e], nr);
                nr += __shfl_xor(nr, 16);
                nr += __shfl_xor(nr, 32);
                if (kg == 0) nrmP[node0 + arow] = nr;
                *(short8*)(hiP + (node0 + arow) * 32 + kg * 8) = Ah;
                *(short8*)(loP + (node0 + arow) * 32 + kg * 8) = Al;
            }

            f32x4 acc0 = {bias0, bias0, bias0, bias0};
            f32x4 acc1 = {bias1, bias1, bias1, bias1};
            acc0 = __builtin_amdgcn_mfma_f32_16x16x32_bf16(Al, Bh0, acc0, 0, 0, 0);
            acc0 = __builtin_amdgcn_mfma_f32_16x16x32_bf16(Ah, Bl0, acc0, 0, 0, 0);
            acc0 = __builtin_amdgcn_mfma_f32_16x16x32_bf16(Ah, Bh0, acc0, 0, 0, 0);
            acc1 = __builtin_amdgcn_mfma_f32_16x16x32_bf16(Al, Bh1, acc1, 0, 0, 0);
            acc1 = __builtin_amdgcn_mfma_f32_16x16x32_bf16(Ah, Bl1, acc1, 0, 0, 0);
            acc1 = __builtin_amdgcn_mfma_f32_16x16x32_bf16(Ah, Bh1, acc1, 0, 0, 0);

            int drow = tb + kg * 4;
            if (ph < 2) {
#pragma unroll
                for (int r = 0; r < 4; r++) {
                    float v0 = elu_f(acc0[r]);
                    float v1 = elu_f(acc1[r]);
                    sx[(drow + r) * 32 + c] = v0;
                    sx[(drow + r) * 32 + 16 + c] = v1;
                    if (MODE == 1 && ph == 1) {
                        size_t off = (node0 + drow + r) * 32 + c;
                        enc[off] = v0;
                        enc[off + 16] = v1;
                    }
                }
            } else {
#pragma unroll
                for (int r = 0; r < 4; r++) {
                    size_t off = (node0 + drow + r) * 32 + c;
                    e1[off] = acc0[r];
                    e1[off + 16] = acc1[r];
                }
            }
        }
    }
}

// 1088 blocks: sv(64) | trk(512) | pfc(512); 256 nodes/block
__global__ __launch_bounds__(256) void encode_all_kernel(
    const float* __restrict__ x_sv, const float* __restrict__ x_trk, const float* __restrict__ x_pfc,
    const float* __restrict__ sv_W1, const float* __restrict__ sv_b1,
    const float* __restrict__ sv_W2, const float* __restrict__ sv_b2,
    const float* __restrict__ trk_W1, const float* __restrict__ trk_b1,
    const float* __restrict__ trk_W2, const float* __restrict__ trk_b2,
    const float* __restrict__ pfc_W1, const float* __restrict__ pfc_b1,
    const float* __restrict__ pfc_W2, const float* __restrict__ pfc_b2,
    const float* __restrict__ conv_W, const float* __restrict__ conv_b,
    float* __restrict__ trk_enc,
    float* __restrict__ Y1, float* __restrict__ Y2,
    float* __restrict__ f1base,
    unsigned short* __restrict__ svHi, unsigned short* __restrict__ svLo, float* __restrict__ nrm_sv,
    unsigned short* __restrict__ pfcHi, unsigned short* __restrict__ pfcLo, float* __restrict__ nrm_pfc)
{
    __shared__ float sx[8192];
    int bid = blockIdx.x;
    if (bid < 64)
        encode_mfma_body<14, 0>(x_sv, sv_W1, sv_b1, sv_W2, sv_b2, conv_W, conv_b,
                                nullptr, Y1, svHi, svLo, nrm_sv, bid, sx);
    else if (bid < 576)
        encode_mfma_body<30, 1>(x_trk, trk_W1, trk_b1, trk_W2, trk_b2, conv_W, conv_b,
                                trk_enc, f1base, nullptr, nullptr, nullptr, bid - 64, sx);
    else
        encode_mfma_body<10, 0>(x_pfc, pfc_W1, pfc_b1, pfc_W2, pfc_b2, conv_W, conv_b,
                                nullptr, Y2, pfcHi, pfcLo, nrm_pfc, bid - 576, sx);
}

// ================= kNN via MFMA Gram tiles (r4/r7/r8/r10-validated) ========
__device__ __forceinline__ void knn_build_B(const float* __restrict__ dstF,
                                            int dstbase, int c, int kg,
                                            short8& Bh, short8& Bl, float& nd)
{
    const float* brow = dstF + (size_t)(dstbase + c) * 32 + kg * 8;
    float4 b0 = *(const float4*)(brow);
    float4 b1 = *(const float4*)(brow + 4);
    float bx[8] = {b0.x, b0.y, b0.z, b0.w, b1.x, b1.y, b1.z, b1.w};
    nd = 0.f;
#pragma unroll
    for (int i = 0; i < 8; i++) {
        float xv = bx[i];
        nd = fmaf(xv, xv, nd);
        short h, l;
        bfsplit(xv, h, l);
        Bh[i] = h; Bl[i] = l;
    }
    nd += __shfl_xor(nd, 16);
    nd += __shfl_xor(nd, 32);
}

// candidate batch over tiles (t0, t0+1) -> 8 keys
__device__ __forceinline__ void knn_batch(
    const unsigned short* __restrict__ srcHi, const unsigned short* __restrict__ srcLo,
    const float* __restrict__ snrm,
    short8 Bh, short8 Bl, float nd, int c, int kg, int t0,
    unsigned* cand)
{
#pragma unroll
    for (int u = 0; u < 2; u++) {
        int tt = t0 + u;
        size_t arow = ((size_t)(tt * 16 + c)) * 32 + (size_t)kg * 8;
        short8 Ah = *(const short8*)(srcHi + arow);
        short8 Al = *(const short8*)(srcLo + arow);
        f32x4 acc = {0.f, 0.f, 0.f, 0.f};
        acc = __builtin_amdgcn_mfma_f32_16x16x32_bf16(Al, Bl, acc, 0, 0, 0);
        acc = __builtin_amdgcn_mfma_f32_16x16x32_bf16(Al, Bh, acc, 0, 0, 0);
        acc = __builtin_amdgcn_mfma_f32_16x16x32_bf16(Ah, Bl, acc, 0, 0, 0);
        acc = __builtin_amdgcn_mfma_f32_16x16x32_bf16(Ah, Bh, acc, 0, 0, 0);
        float4 sn = *(const float4*)(snrm + tt * 16 + kg * 4);
        int sb = tt * 16 + kg * 4;
        cand[u*4+0] = (__float_as_uint(fmaf(-2.f, acc[0], sn.x + nd)) & 0xFFFFFE00u) | (unsigned)(sb + 0);
        cand[u*4+1] = (__float_as_uint(fmaf(-2.f, acc[1], sn.y + nd)) & 0xFFFFFE00u) | (unsigned)(sb + 1);
        cand[u*4+2] = (__float_as_uint(fmaf(-2.f, acc[2], sn.z + nd)) & 0xFFFFFE00u) | (unsigned)(sb + 2);
        cand[u*4+3] = (__float_as_uint(fmaf(-2.f, acc[3], sn.w + nd)) & 0xFFFFFE00u) | (unsigned)(sb + 3);
    }
}

// single-chain scan (short src sets, NT even)
template<int NT>
__device__ __forceinline__ void knn_scan(
    const unsigned short* __restrict__ srcHi, const unsigned short* __restrict__ srcLo,
    const float* __restrict__ snrm,
    short8 Bh, short8 Bl, float nd, int c, int kg,
    unsigned* key)
{
    for (int t = 0; t < NT; t += 2) {
        unsigned cand[8];
        knn_batch(srcHi, srcLo, snrm, Bh, Bl, nd, c, kg, t, cand);
        sort8(cand);
        merge8(key, cand);
    }
}

// dual-chain 32-tile scan: chains over tiles [0,16) and [16,32) are fully
// independent (loads+MFMAs of one overlap the sort network of the other),
// merged once at the end. Keys unique -> final top-8 bit-identical to the
// sequential scan.
__device__ __forceinline__ void knn_scan32_dual(
    const unsigned short* __restrict__ srcHi, const unsigned short* __restrict__ srcLo,
    const float* __restrict__ snrm,
    short8 Bh, short8 Bl, float nd, int c, int kg,
    unsigned* key)
{
    unsigned keyB[8];
#pragma unroll
    for (int k = 0; k < 8; k++) keyB[k] = 0xFFFFFFFFu;
    for (int t = 0; t < 16; t += 2) {
        unsigned ca[8], cb[8];
        knn_batch(srcHi, srcLo, snrm, Bh, Bl, nd, c, kg, t, ca);
        knn_batch(srcHi, srcLo, snrm, Bh, Bl, nd, c, kg, 16 + t, cb);
        sort8(ca); merge8(key, ca);
        sort8(cb); merge8(keyB, cb);
    }
    merge8(key, keyB);
}

// after symmetric merges all 4 lanes of a dst column hold the identical
// final sorted top-8 (keys unique -> deterministic).
__device__ __forceinline__ void knn_merge_lanes(unsigned* key)
{
    unsigned oth[8];
#pragma unroll
    for (int k = 0; k < 8; k++) oth[k] = __shfl_xor(key[k], 16);
    merge8(key, oth);
#pragma unroll
    for (int k = 0; k < 8; k++) oth[k] = __shfl_xor(key[k], 32);
    merge8(key, oth);
}

__device__ __forceinline__ void gather_max8(const float* __restrict__ Yb,
                                            const unsigned* key, int kg, float* m)
{
    const float* r0 = Yb + (size_t)(key[0] & 511u) * 32 + kg * 8;
    float4 a = *(const float4*)(r0);
    float4 b = *(const float4*)(r0 + 4);
    m[0] = a.x; m[1] = a.y; m[2] = a.z; m[3] = a.w;
    m[4] = b.x; m[5] = b.y; m[6] = b.z; m[7] = b.w;
#pragma unroll
    for (int k = 1; k < 8; k++) {
        const float* rr = Yb + (size_t)(key[k] & 511u) * 32 + kg * 8;
        float4 va = *(const float4*)(rr);
        float4 vb = *(const float4*)(rr + 4);
        m[0] = fmaxf(m[0], va.x); m[1] = fmaxf(m[1], va.y);
        m[2] = fmaxf(m[2], va.z); m[3] = fmaxf(m[3], va.w);
        m[4] = fmaxf(m[4], vb.x); m[5] = fmaxf(m[5], vb.y);
        m[6] = fmaxf(m[6], vb.z); m[7] = fmaxf(m[7], vb.w);
    }
}

// knn12 + g12 + yb3 fused: 2048 blocks (r10-validated aliasing: Y3=trk_enc,
// B3=f1base; each wave reads only its own 16 rows before overwriting them).
// Also zeroes the per-event completion counters for knn3's fused final.
__global__ __launch_bounds__(256) void knn12_kernel(
    const unsigned short* __restrict__ svHi, const unsigned short* __restrict__ svLo,
    const float* __restrict__ nrm_sv,
    const unsigned short* __restrict__ pfcHi, const unsigned short* __restrict__ pfcLo,
    const float* __restrict__ nrm_pfc,
    const float* __restrict__ trk_enc,
    const float* __restrict__ Y1, const float* __restrict__ Y2,
    const float* __restrict__ f1base, float* __restrict__ f2,
    unsigned short* __restrict__ f1Hi, unsigned short* __restrict__ f1Lo,
    float* __restrict__ nrm_f1,
    float* __restrict__ Y3, float* __restrict__ B3,
    const float* __restrict__ conv_W, const float* __restrict__ conv_b,
    int* __restrict__ cnt)
{
    int bid = blockIdx.x;
    int e = bid & 255, j = bid >> 8;
    int tid = threadIdx.x;
    int lane = tid & 63, wave = tid >> 6;
    int c = lane & 15, kg = lane >> 4;
    int dstbase = j * 64 + wave * 16;
    size_t trow = (size_t)e * 512 + dstbase + c;

    if (j == 0 && tid == 0) cnt[e] = 0;   // reset for knn3's fused final

    // conv weight fragments for the fused Y3/B3 MFMAs (r7 yb3 order)
    short8 WYh0, WYl0, WYh1, WYl1, WDh0, WDl0, WDh1, WDl1;
#pragma unroll
    for (int ee = 0; ee < 8; ee++) {
        int kk = kg * 8 + ee;
        float y0 = conv_W[1024 + kk * 32 + c];
        float y1 = conv_W[1024 + kk * 32 + 16 + c];
        float d0 = conv_W[kk * 32 + c] - y0;
        float d1 = conv_W[kk * 32 + 16 + c] - y1;
        short h, l;
        bfsplit(y0, h, l); WYh0[ee] = h; WYl0[ee] = l;
        bfsplit(y1, h, l); WYh1[ee] = h; WYl1[ee] = l;
        bfsplit(d0, h, l); WDh0[ee] = h; WDl0[ee] = l;
        bfsplit(d1, h, l); WDh1[ee] = h; WDl1[ee] = l;
    }
    float bd0 = conv_b[c], bd1 = conv_b[16 + c];

    short8 Bh, Bl;
    float nd;
    knn_build_B(trk_enc + (size_t)e * 512 * 32, dstbase, c, kg, Bh, Bl, nd);

    unsigned key2[8];
#pragma unroll
    for (int k = 0; k < 8; k++) key2[k] = 0xFFFFFFFFu;
    knn_scan32_dual(pfcHi + (size_t)e * 512 * 32, pfcLo + (size_t)e * 512 * 32,
                    nrm_pfc + e * 512, Bh, Bl, nd, c, kg, key2);
    knn_merge_lanes(key2);

    unsigned key1[8];
#pragma unroll
    for (int k = 0; k < 8; k++) key1[k] = 0xFFFFFFFFu;
    knn_scan<4>(svHi + (size_t)e * 64 * 32, svLo + (size_t)e * 64 * 32,
                nrm_sv + e * 64, Bh, Bl, nd, c, kg, key1);
    knn_merge_lanes(key1);

    // base (read BEFORE B3 overwrites these rows)
    const float* bp = f1base + trow * 32 + kg * 8;
    float4 bb0 = *(const float4*)(bp);
    float4 bb1 = *(const float4*)(bp + 4);
    float base[8] = {bb0.x, bb0.y, bb0.z, bb0.w, bb1.x, bb1.y, bb1.z, bb1.w};

    float m[8];
    // f2 = elu(base + max Y2[rows2]); keep split for B3
    gather_max8(Y2 + (size_t)e * 512 * 32, key2, kg, m);
    float v2[8];
    short8 Fh, Fl;
#pragma unroll
    for (int i = 0; i < 8; i++) {
        v2[i] = elu_f(base[i] + m[i]);
        short h, l;
        bfsplit(v2[i], h, l);
        Fh[i] = h; Fl[i] = l;
    }
    {
        float4* op = (float4*)(f2 + trow * 32 + kg * 8);
        op[0] = (float4){v2[0], v2[1], v2[2], v2[3]};
        op[1] = (float4){v2[4], v2[5], v2[6], v2[7]};
    }

    // f1 = elu(base + max Y1[rows1]) -> planes + norm (kept in regs)
    gather_max8(Y1 + (size_t)e * 64 * 32, key1, kg, m);
    float v1[8];
    float nr = 0.f;
    short8 Hh, Hl;
#pragma unroll
    for (int i = 0; i < 8; i++) {
        v1[i] = elu_f(base[i] + m[i]);
        nr = fmaf(v1[i], v1[i], nr);
        short h, l;
        bfsplit(v1[i], h, l);
        Hh[i] = h; Hl[i] = l;
    }
    nr += __shfl_xor(nr, 16);
    nr += __shfl_xor(nr, 32);
    if (kg == 0) nrm_f1[trow] = nr;
    *(short8*)(f1Hi + trow * 32 + kg * 8) = Hh;
    *(short8*)(f1Lo + trow * 32 + kg * 8) = Hl;

    // Y3 = f1 @ w2h (bias 0) for this wave's 16 dst rows (r7 yb3 order)
    f32x4 a0 = {0.f, 0.f, 0.f, 0.f}, a1 = {0.f, 0.f, 0.f, 0.f};
    a0 = __builtin_amdgcn_mfma_f32_16x16x32_bf16(Hl, WYh0, a0, 0, 0, 0);
    a0 = __builtin_amdgcn_mfma_f32_16x16x32_bf16(Hh, WYl0, a0, 0, 0, 0);
    a0 = __builtin_amdgcn_mfma_f32_16x16x32_bf16(Hh, WYh0, a0, 0, 0, 0);
    a1 = __builtin_amdgcn_mfma_f32_16x16x32_bf16(Hl, WYh1, a1, 0, 0, 0);
    a1 = __builtin_amdgcn_mfma_f32_16x16x32_bf16(Hh, WYl1, a1, 0, 0, 0);
    a1 = __builtin_amdgcn_mfma_f32_16x16x32_bf16(Hh, WYh1, a1, 0, 0, 0);
    // B3 = f2 @ wd + conv_b
    f32x4 q0 = {bd0, bd0, bd0, bd0}, q1 = {bd1, bd1, bd1, bd1};
    q0 = __builtin_amdgcn_mfma_f32_16x16x32_bf16(Fl, WDh0, q0, 0, 0, 0);
    q0 = __builtin_amdgcn_mfma_f32_16x16x32_bf16(Fh, WDl0, q0, 0, 0, 0);
    q0 = __builtin_amdgcn_mfma_f32_16x16x32_bf16(Fh, WDh0, q0, 0, 0, 0);
    q1 = __builtin_amdgcn_mfma_f32_16x16x32_bf16(Fl, WDh1, q1, 0, 0, 0);
    q1 = __builtin_amdgcn_mfma_f32_16x16x32_bf16(Fh, WDl1, q1, 0, 0, 0);
    q1 = __builtin_amdgcn_mfma_f32_16x16x32_bf16(Fh, WDh1, q1, 0, 0, 0);

    int drow = dstbase + kg * 4;
#pragma unroll
    for (int r = 0; r < 4; r++) {
        size_t off = ((size_t)e * 512 + drow + r) * 32 + c;
        Y3[off] = a0[r];  Y3[off + 16] = a1[r];
        B3[off] = q0[r];  B3[off + 16] = q1[r];
    }
}

// knn3 + g3 + final fused: 2048 blocks. After writing its pool partial, each
// block fences + bumps the event counter; the 8th finisher runs the MLP.
__global__ __launch_bounds__(256) void knn3_kernel(
    const unsigned short* __restrict__ f1Hi, const unsigned short* __restrict__ f1Lo,
    const float* __restrict__ nrm_f1,
    const float* __restrict__ f2,
    const float* __restrict__ Y3, const float* __restrict__ B3,
    float* __restrict__ pool, int* __restrict__ cnt,
    const float* __restrict__ out_W1, const float* __restrict__ out_b1,
    const float* __restrict__ out_W2, const float* __restrict__ out_b2,
    float* __restrict__ outp)
{
    __shared__ float sp[4][32];
    __shared__ float spf[32];
    __shared__ float sh1[32];
    __shared__ int sflag;
    int bid = blockIdx.x;
    int e = bid & 255, j = bid >> 8;
    int tid = threadIdx.x;
    int lane = tid & 63, wave = tid >> 6;
    int c = lane & 15, kg = lane >> 4;
    int dstbase = j * 64 + wave * 16;
    size_t trow = (size_t)e * 512 + dstbase + c;

    short8 Bh, Bl;
    float nd;
    knn_build_B(f2 + (size_t)e * 512 * 32, dstbase, c, kg, Bh, Bl, nd);

    unsigned key[8];
#pragma unroll
    for (int k = 0; k < 8; k++) key[k] = 0xFFFFFFFFu;
    knn_scan32_dual(f1Hi + (size_t)e * 512 * 32, f1Lo + (size_t)e * 512 * 32,
                    nrm_f1 + e * 512, Bh, Bl, nd, c, kg, key);
    knn_merge_lanes(key);

    float m[8];
    gather_max8(Y3 + (size_t)e * 512 * 32, key, kg, m);

    const float* bp = B3 + trow * 32 + kg * 8;
    float4 bb0 = *(const float4*)(bp);
    float4 bb1 = *(const float4*)(bp + 4);
    float base[8] = {bb0.x, bb0.y, bb0.z, bb0.w, bb1.x, bb1.y, bb1.z, bb1.w};

    float r[8];
#pragma unroll
    for (int i = 0; i < 8; i++) r[i] = elu_f(base[i] + m[i]);

#pragma unroll
    for (int off = 1; off < 16; off <<= 1) {
#pragma unroll
        for (int i = 0; i < 8; i++) r[i] += __shfl_xor(r[i], off);
    }
    if (c == 0) {
#pragma unroll
        for (int i = 0; i < 8; i++) sp[wave][kg * 8 + i] = r[i];
    }
    __syncthreads();
    if (tid < 32)
        pool[((size_t)e * 8 + j) * 32 + tid] =
            sp[0][tid] + sp[1][tid] + sp[2][tid] + sp[3][tid];

    // ---- last-block-per-event final MLP ----------------------------------
    __threadfence();                    // publish pool partial device-wide
    __syncthreads();                    // all lanes' stores drained
    if (tid == 0) {
        int old = atomicAdd(&cnt[e], 1);
        sflag = (old == 7);
    }
    __syncthreads();
    if (sflag) {
        __threadfence();                // acquire other blocks' pool writes
        if (tid < 32) {
            float s = 0.f;
#pragma unroll
            for (int jj = 0; jj < 8; jj++)
                s += pool[((size_t)e * 8 + jj) * 32 + tid];
            spf[tid] = s * (1.0f / 512.0f);
        }
        __syncthreads();
        if (tid < 32) {
            float h = out_b1[tid];
#pragma unroll
            for (int d = 0; d < 32; d++)
                h = fmaf(spf[d], out_W1[d * 32 + tid], h);
            sh1[tid] = elu_f(h);
        }
        __syncthreads();
        if (tid == 0) {
            float o = out_b2[0];
#pragma unroll
            for (int d = 0; d < 32; d++) o = fmaf(sh1[d], out_W2[d], o);
            o = 1.f / (1.f + __expf(-o));
            outp[e] = o;
            outp[NB + e] = (float)e;
        }
    }
}

extern "C" void kernel_launch(void* const* d_in, const int* in_sizes, int n_in,
                              void* d_out, int out_size, void* d_ws, size_t ws_size,
                              hipStream_t stream) {
    const float* x_sv  = (const float*)d_in[0];
    const float* x_trk = (const float*)d_in[1];
    const float* x_pfc = (const float*)d_in[2];
    const float* sv_W1  = (const float*)d_in[6];
    const float* sv_b1  = (const float*)d_in[7];
    const float* sv_W2  = (const float*)d_in[8];
    const float* sv_b2  = (const float*)d_in[9];
    const float* trk_W1 = (const float*)d_in[10];
    const float* trk_b1 = (const float*)d_in[11];
    const float* trk_W2 = (const float*)d_in[12];
    const float* trk_b2 = (const float*)d_in[13];
    const float* pfc_W1 = (const float*)d_in[14];
    const float* pfc_b1 = (const float*)d_in[15];
    const float* pfc_W2 = (const float*)d_in[16];
    const float* pfc_b2 = (const float*)d_in[17];
    const float* conv_W = (const float*)d_in[18];
    const float* conv_b = (const float*)d_in[19];
    const float* out_W1 = (const float*)d_in[20];
    const float* out_b1 = (const float*)d_in[21];
    const float* out_W2 = (const float*)d_in[22];
    const float* out_b2 = (const float*)d_in[23];

    float* ws = (float*)d_ws;
    const size_t SV_E  = (size_t)NB * 64 * 32;     //   524288
    const size_t TRK_E = (size_t)NB * 512 * 32;    //  4194304
    float* f1base  = ws;                           // B3 aliases (in knn12)
    float* f2      = f1base + TRK_E;
    float* trk_enc = f2 + TRK_E;                   // Y3 aliases (in knn12)
    float* Y1      = trk_enc + TRK_E;
    float* Y2      = Y1 + SV_E;
    unsigned short* svHi  = (unsigned short*)(Y2 + TRK_E);   // SV_E u16
    unsigned short* svLo  = svHi + SV_E;                     // pool aliases
    unsigned short* pfcHi = svLo + SV_E;                     // TRK_E u16
    unsigned short* pfcLo = pfcHi + TRK_E;
    unsigned short* f1Hi  = pfcLo + TRK_E;
    unsigned short* f1Lo  = f1Hi + TRK_E;
    float* nrm_sv  = (float*)(f1Lo + TRK_E);                 // NB*64
    float* nrm_pfc = nrm_sv + (size_t)NB * 64;               // NB*512
    float* nrm_f1  = nrm_pfc + (size_t)NB * 512;             // NB*512
    int*   cnt     = (int*)(nrm_f1 + (size_t)NB * 512);      // NB i32
    float* Y3   = trk_enc;          // each wave reads-then-writes own rows
    float* B3   = f1base;           // same argument
    float* pool = (float*)svHi;     // sv planes dead after knn12; NB*8*32 f32

    encode_all_kernel<<<1088, 256, 0, stream>>>(
        x_sv, x_trk, x_pfc,
        sv_W1, sv_b1, sv_W2, sv_b2,
        trk_W1, trk_b1, trk_W2, trk_b2,
        pfc_W1, pfc_b1, pfc_W2, pfc_b2,
        conv_W, conv_b,
        trk_enc, Y1, Y2, f1base,
        svHi, svLo, nrm_sv, pfcHi, pfcLo, nrm_pfc);

    knn12_kernel<<<2048, 256, 0, stream>>>(svHi, svLo, nrm_sv,
                                           pfcHi, pfcLo, nrm_pfc,
                                           trk_enc, Y1, Y2,
                                           f1base, f2, f1Hi, f1Lo, nrm_f1,
                                           Y3, B3, conv_W, conv_b, cnt);

    knn3_kernel<<<2048, 256, 0, stream>>>(f1Hi, f1Lo, nrm_f1, f2, Y3, B3,
                                          pool, cnt,
                                          out_W1, out_b1, out_W2, out_b2,
                                          (float*)d_out);
}

// Round 12
// 296.579 us; speedup vs baseline: 1.6106x; 1.6106x over previous
//
#include <hip/hip_runtime.h>
#include <math.h>

#define NB 256      // events
#define KNN 8

typedef __attribute__((ext_vector_type(8))) short short8;
typedef __attribute__((ext_vector_type(4))) float f32x4;

__device__ __forceinline__ float elu_f(float x) {
    return x > 0.f ? x : __expf(x) - 1.f;
}

// round-to-nearest-even fp32 -> bf16 (returns low 16 bits)
__device__ __forceinline__ unsigned bf16rn(float x) {
    unsigned u = __float_as_uint(x);
    return (u + 0x7FFFu + ((u >> 16) & 1u)) >> 16;
}

// split fp32 -> (hi, lo) bf16 pair
__device__ __forceinline__ void bfsplit(float x, short& h, short& l) {
    unsigned hu = bf16rn(x);
    h = (short)hu;
    l = (short)bf16rn(x - __uint_as_float(hu << 16));
}

// ---- sorting-network primitives on u32 keys (validated r1-r10) ------------
__device__ __forceinline__ void cex(unsigned& a, unsigned& b) {
    unsigned lo = min(a, b), hi = max(a, b);
    a = lo; b = hi;
}

__device__ __forceinline__ void sort8(unsigned* s) {
    cex(s[0], s[1]); cex(s[2], s[3]); cex(s[4], s[5]); cex(s[6], s[7]);
    cex(s[0], s[2]); cex(s[1], s[3]); cex(s[4], s[6]); cex(s[5], s[7]);
    cex(s[1], s[2]); cex(s[5], s[6]);
    cex(s[0], s[4]); cex(s[1], s[5]); cex(s[2], s[6]); cex(s[3], s[7]);
    cex(s[2], s[4]); cex(s[3], s[5]);
    cex(s[1], s[2]); cex(s[3], s[4]); cex(s[5], s[6]);
}

__device__ __forceinline__ void merge8(unsigned* v, const unsigned* s) {
#pragma unroll
    for (int i = 0; i < 8; i++) v[i] = min(v[i], s[7 - i]);
    cex(v[0], v[4]); cex(v[1], v[5]); cex(v[2], v[6]); cex(v[3], v[7]);
    cex(v[0], v[2]); cex(v[1], v[3]); cex(v[4], v[6]); cex(v[5], v[7]);
    cex(v[0], v[1]); cex(v[2], v[3]); cex(v[4], v[5]); cex(v[6], v[7]);
}

// ================= MFMA encoder (r6-validated) =============================
template<int FIN, int MODE>
__device__ void encode_mfma_body(const float* __restrict__ x,
    const float* __restrict__ W1, const float* __restrict__ b1,
    const float* __restrict__ W2, const float* __restrict__ b2,
    const float* __restrict__ conv_W, const float* __restrict__ conv_b,
    float* __restrict__ enc, float* __restrict__ e1,
    unsigned short* __restrict__ hiP, unsigned short* __restrict__ loP,
    float* __restrict__ nrmP,
    int blk, float* __restrict__ sx)
{
    int tid = threadIdx.x;
    int lane = tid & 63, wv = tid >> 6;
    int c = lane & 15, kg = lane >> 4;
    size_t node0 = (size_t)blk * 256;

    {
        const float* xb = x + node0 * FIN;
        for (int i = tid; i < 8192; i += 256) {
            int n = i >> 5, f = i & 31;
            sx[i] = (f < FIN) ? xb[n * FIN + f] : 0.f;
        }
    }
    __syncthreads();

    int rb = wv * 64;

#pragma unroll
    for (int ph = 0; ph < 3; ph++) {
        short8 Bh0, Bl0, Bh1, Bl1;
#pragma unroll
        for (int e = 0; e < 8; e++) {
            int kk = kg * 8 + e;
            float w0, w1;
            if (ph == 0) {
                w0 = (kk < FIN) ? W1[kk * 32 + c] : 0.f;
                w1 = (kk < FIN) ? W1[kk * 32 + 16 + c] : 0.f;
            } else if (ph == 1) {
                w0 = W2[kk * 32 + c];
                w1 = W2[kk * 32 + 16 + c];
            } else {
                w0 = conv_W[1024 + kk * 32 + c];
                w1 = conv_W[1024 + kk * 32 + 16 + c];
                if (MODE == 1) {
                    w0 = conv_W[kk * 32 + c] - w0;
                    w1 = conv_W[kk * 32 + 16 + c] - w1;
                }
            }
            short h, l;
            bfsplit(w0, h, l); Bh0[e] = h; Bl0[e] = l;
            bfsplit(w1, h, l); Bh1[e] = h; Bl1[e] = l;
        }
        float bias0, bias1;
        if (ph == 0)      { bias0 = b1[c]; bias1 = b1[16 + c]; }
        else if (ph == 1) { bias0 = b2[c]; bias1 = b2[16 + c]; }
        else              { bias0 = (MODE == 1) ? conv_b[c] : 0.f;
                            bias1 = (MODE == 1) ? conv_b[16 + c] : 0.f; }

#pragma unroll
        for (int t = 0; t < 4; t++) {
            int tb = rb + t * 16;
            int arow = tb + c;
            const float* ap = sx + arow * 32 + kg * 8;
            float4 a0 = *(const float4*)(ap);
            float4 a1 = *(const float4*)(ap + 4);
            float av[8] = {a0.x, a0.y, a0.z, a0.w, a1.x, a1.y, a1.z, a1.w};
            short8 Ah, Al;
#pragma unroll
            for (int e = 0; e < 8; e++) {
                short h, l;
                bfsplit(av[e], h, l);
                Ah[e] = h; Al[e] = l;
            }

            if (MODE == 0 && ph == 2) {
                float nr = 0.f;
#pragma unroll
                for (int e = 0; e < 8; e++) nr = fmaf(av[e], av[e], nr);
                nr += __shfl_xor(nr, 16);
                nr += __shfl_xor(nr, 32);
                if (kg == 0) nrmP[node0 + arow] = nr;
                *(short8*)(hiP + (node0 + arow) * 32 + kg * 8) = Ah;
                *(short8*)(loP + (node0 + arow) * 32 + kg * 8) = Al;
            }

            f32x4 acc0 = {bias0, bias0, bias0, bias0};
            f32x4 acc1 = {bias1, bias1, bias1, bias1};
            acc0 = __builtin_amdgcn_mfma_f32_16x16x32_bf16(Al, Bh0, acc0, 0, 0, 0);
            acc0 = __builtin_amdgcn_mfma_f32_16x16x32_bf16(Ah, Bl0, acc0, 0, 0, 0);
            acc0 = __builtin_amdgcn_mfma_f32_16x16x32_bf16(Ah, Bh0, acc0, 0, 0, 0);
            acc1 = __builtin_amdgcn_mfma_f32_16x16x32_bf16(Al, Bh1, acc1, 0, 0, 0);
            acc1 = __builtin_amdgcn_mfma_f32_16x16x32_bf16(Ah, Bl1, acc1, 0, 0, 0);
            acc1 = __builtin_amdgcn_mfma_f32_16x16x32_bf16(Ah, Bh1, acc1, 0, 0, 0);

            int drow = tb + kg * 4;
            if (ph < 2) {
#pragma unroll
                for (int r = 0; r < 4; r++) {
                    float v0 = elu_f(acc0[r]);
                    float v1 = elu_f(acc1[r]);
                    sx[(drow + r) * 32 + c] = v0;
                    sx[(drow + r) * 32 + 16 + c] = v1;
                    if (MODE == 1 && ph == 1) {
                        size_t off = (node0 + drow + r) * 32 + c;
                        enc[off] = v0;
                        enc[off + 16] = v1;
                    }
                }
            } else {
#pragma unroll
                for (int r = 0; r < 4; r++) {
                    size_t off = (node0 + drow + r) * 32 + c;
                    e1[off] = acc0[r];
                    e1[off + 16] = acc1[r];
                }
            }
        }
    }
}

// 1088 blocks: sv(64) | trk(512) | pfc(512); 256 nodes/block
__global__ __launch_bounds__(256) void encode_all_kernel(
    const float* __restrict__ x_sv, const float* __restrict__ x_trk, const float* __restrict__ x_pfc,
    const float* __restrict__ sv_W1, const float* __restrict__ sv_b1,
    const float* __restrict__ sv_W2, const float* __restrict__ sv_b2,
    const float* __restrict__ trk_W1, const float* __restrict__ trk_b1,
    const float* __restrict__ trk_W2, const float* __restrict__ trk_b2,
    const float* __restrict__ pfc_W1, const float* __restrict__ pfc_b1,
    const float* __restrict__ pfc_W2, const float* __restrict__ pfc_b2,
    const float* __restrict__ conv_W, const float* __restrict__ conv_b,
    float* __restrict__ trk_enc,
    float* __restrict__ Y1, float* __restrict__ Y2,
    float* __restrict__ f1base,
    unsigned short* __restrict__ svHi, unsigned short* __restrict__ svLo, float* __restrict__ nrm_sv,
    unsigned short* __restrict__ pfcHi, unsigned short* __restrict__ pfcLo, float* __restrict__ nrm_pfc)
{
    __shared__ float sx[8192];
    int bid = blockIdx.x;
    if (bid < 64)
        encode_mfma_body<14, 0>(x_sv, sv_W1, sv_b1, sv_W2, sv_b2, conv_W, conv_b,
                                nullptr, Y1, svHi, svLo, nrm_sv, bid, sx);
    else if (bid < 576)
        encode_mfma_body<30, 1>(x_trk, trk_W1, trk_b1, trk_W2, trk_b2, conv_W, conv_b,
                                trk_enc, f1base, nullptr, nullptr, nullptr, bid - 64, sx);
    else
        encode_mfma_body<10, 0>(x_pfc, pfc_W1, pfc_b1, pfc_W2, pfc_b2, conv_W, conv_b,
                                nullptr, Y2, pfcHi, pfcLo, nrm_pfc, bid - 576, sx);
}

// ================= kNN via MFMA Gram tiles (r4/r7/r8/r10-validated) ========
__device__ __forceinline__ void knn_build_B(const float* __restrict__ dstF,
                                            int dstbase, int c, int kg,
                                            short8& Bh, short8& Bl, float& nd)
{
    const float* brow = dstF + (size_t)(dstbase + c) * 32 + kg * 8;
    float4 b0 = *(const float4*)(brow);
    float4 b1 = *(const float4*)(brow + 4);
    float bx[8] = {b0.x, b0.y, b0.z, b0.w, b1.x, b1.y, b1.z, b1.w};
    nd = 0.f;
#pragma unroll
    for (int i = 0; i < 8; i++) {
        float xv = bx[i];
        nd = fmaf(xv, xv, nd);
        short h, l;
        bfsplit(xv, h, l);
        Bh[i] = h; Bl[i] = l;
    }
    nd += __shfl_xor(nd, 16);
    nd += __shfl_xor(nd, 32);
}

// candidate batch over tiles (t0, t0+1) -> 8 keys
__device__ __forceinline__ void knn_batch(
    const unsigned short* __restrict__ srcHi, const unsigned short* __restrict__ srcLo,
    const float* __restrict__ snrm,
    short8 Bh, short8 Bl, float nd, int c, int kg, int t0,
    unsigned* cand)
{
#pragma unroll
    for (int u = 0; u < 2; u++) {
        int tt = t0 + u;
        size_t arow = ((size_t)(tt * 16 + c)) * 32 + (size_t)kg * 8;
        short8 Ah = *(const short8*)(srcHi + arow);
        short8 Al = *(const short8*)(srcLo + arow);
        f32x4 acc = {0.f, 0.f, 0.f, 0.f};
        acc = __builtin_amdgcn_mfma_f32_16x16x32_bf16(Al, Bl, acc, 0, 0, 0);
        acc = __builtin_amdgcn_mfma_f32_16x16x32_bf16(Al, Bh, acc, 0, 0, 0);
        acc = __builtin_amdgcn_mfma_f32_16x16x32_bf16(Ah, Bl, acc, 0, 0, 0);
        acc = __builtin_amdgcn_mfma_f32_16x16x32_bf16(Ah, Bh, acc, 0, 0, 0);
        float4 sn = *(const float4*)(snrm + tt * 16 + kg * 4);
        int sb = tt * 16 + kg * 4;
        cand[u*4+0] = (__float_as_uint(fmaf(-2.f, acc[0], sn.x + nd)) & 0xFFFFFE00u) | (unsigned)(sb + 0);
        cand[u*4+1] = (__float_as_uint(fmaf(-2.f, acc[1], sn.y + nd)) & 0xFFFFFE00u) | (unsigned)(sb + 1);
        cand[u*4+2] = (__float_as_uint(fmaf(-2.f, acc[2], sn.z + nd)) & 0xFFFFFE00u) | (unsigned)(sb + 2);
        cand[u*4+3] = (__float_as_uint(fmaf(-2.f, acc[3], sn.w + nd)) & 0xFFFFFE00u) | (unsigned)(sb + 3);
    }
}

// single-chain scan (short src sets, NT even)
template<int NT>
__device__ __forceinline__ void knn_scan(
    const unsigned short* __restrict__ srcHi, const unsigned short* __restrict__ srcLo,
    const float* __restrict__ snrm,
    short8 Bh, short8 Bl, float nd, int c, int kg,
    unsigned* key)
{
    for (int t = 0; t < NT; t += 2) {
        unsigned cand[8];
        knn_batch(srcHi, srcLo, snrm, Bh, Bl, nd, c, kg, t, cand);
        sort8(cand);
        merge8(key, cand);
    }
}

// dual-chain 32-tile scan: chains over tiles [0,16) and [16,32) are fully
// independent (loads+MFMAs of one overlap the sort network of the other),
// merged once at the end. Keys unique -> final top-8 bit-identical to the
// sequential scan.
__device__ __forceinline__ void knn_scan32_dual(
    const unsigned short* __restrict__ srcHi, const unsigned short* __restrict__ srcLo,
    const float* __restrict__ snrm,
    short8 Bh, short8 Bl, float nd, int c, int kg,
    unsigned* key)
{
    unsigned keyB[8];
#pragma unroll
    for (int k = 0; k < 8; k++) keyB[k] = 0xFFFFFFFFu;
    for (int t = 0; t < 16; t += 2) {
        unsigned ca[8], cb[8];
        knn_batch(srcHi, srcLo, snrm, Bh, Bl, nd, c, kg, t, ca);
        knn_batch(srcHi, srcLo, snrm, Bh, Bl, nd, c, kg, 16 + t, cb);
        sort8(ca); merge8(key, ca);
        sort8(cb); merge8(keyB, cb);
    }
    merge8(key, keyB);
}

// after symmetric merges all 4 lanes of a dst column hold the identical
// final sorted top-8 (keys unique -> deterministic).
__device__ __forceinline__ void knn_merge_lanes(unsigned* key)
{
    unsigned oth[8];
#pragma unroll
    for (int k = 0; k < 8; k++) oth[k] = __shfl_xor(key[k], 16);
    merge8(key, oth);
#pragma unroll
    for (int k = 0; k < 8; k++) oth[k] = __shfl_xor(key[k], 32);
    merge8(key, oth);
}

__device__ __forceinline__ void gather_max8(const float* __restrict__ Yb,
                                            const unsigned* key, int kg, float* m)
{
    const float* r0 = Yb + (size_t)(key[0] & 511u) * 32 + kg * 8;
    float4 a = *(const float4*)(r0);
    float4 b = *(const float4*)(r0 + 4);
    m[0] = a.x; m[1] = a.y; m[2] = a.z; m[3] = a.w;
    m[4] = b.x; m[5] = b.y; m[6] = b.z; m[7] = b.w;
#pragma unroll
    for (int k = 1; k < 8; k++) {
        const float* rr = Yb + (size_t)(key[k] & 511u) * 32 + kg * 8;
        float4 va = *(const float4*)(rr);
        float4 vb = *(const float4*)(rr + 4);
        m[0] = fmaxf(m[0], va.x); m[1] = fmaxf(m[1], va.y);
        m[2] = fmaxf(m[2], va.z); m[3] = fmaxf(m[3], va.w);
        m[4] = fmaxf(m[4], vb.x); m[5] = fmaxf(m[5], vb.y);
        m[6] = fmaxf(m[6], vb.z); m[7] = fmaxf(m[7], vb.w);
    }
}

// knn12 + g12 + yb3 fused: 2048 blocks (r10-validated aliasing: Y3=trk_enc,
// B3=f1base; each wave reads only its own 16 rows before overwriting them).
__global__ __launch_bounds__(256) void knn12_kernel(
    const unsigned short* __restrict__ svHi, const unsigned short* __restrict__ svLo,
    const float* __restrict__ nrm_sv,
    const unsigned short* __restrict__ pfcHi, const unsigned short* __restrict__ pfcLo,
    const float* __restrict__ nrm_pfc,
    const float* __restrict__ trk_enc,
    const float* __restrict__ Y1, const float* __restrict__ Y2,
    const float* __restrict__ f1base, float* __restrict__ f2,
    unsigned short* __restrict__ f1Hi, unsigned short* __restrict__ f1Lo,
    float* __restrict__ nrm_f1,
    float* __restrict__ Y3, float* __restrict__ B3,
    const float* __restrict__ conv_W, const float* __restrict__ conv_b)
{
    int bid = blockIdx.x;
    int e = bid & 255, j = bid >> 8;
    int tid = threadIdx.x;
    int lane = tid & 63, wave = tid >> 6;
    int c = lane & 15, kg = lane >> 4;
    int dstbase = j * 64 + wave * 16;
    size_t trow = (size_t)e * 512 + dstbase + c;

    // conv weight fragments for the fused Y3/B3 MFMAs (r7 yb3 order)
    short8 WYh0, WYl0, WYh1, WYl1, WDh0, WDl0, WDh1, WDl1;
#pragma unroll
    for (int ee = 0; ee < 8; ee++) {
        int kk = kg * 8 + ee;
        float y0 = conv_W[1024 + kk * 32 + c];
        float y1 = conv_W[1024 + kk * 32 + 16 + c];
        float d0 = conv_W[kk * 32 + c] - y0;
        float d1 = conv_W[kk * 32 + 16 + c] - y1;
        short h, l;
        bfsplit(y0, h, l); WYh0[ee] = h; WYl0[ee] = l;
        bfsplit(y1, h, l); WYh1[ee] = h; WYl1[ee] = l;
        bfsplit(d0, h, l); WDh0[ee] = h; WDl0[ee] = l;
        bfsplit(d1, h, l); WDh1[ee] = h; WDl1[ee] = l;
    }
    float bd0 = conv_b[c], bd1 = conv_b[16 + c];

    short8 Bh, Bl;
    float nd;
    knn_build_B(trk_enc + (size_t)e * 512 * 32, dstbase, c, kg, Bh, Bl, nd);

    unsigned key2[8];
#pragma unroll
    for (int k = 0; k < 8; k++) key2[k] = 0xFFFFFFFFu;
    knn_scan32_dual(pfcHi + (size_t)e * 512 * 32, pfcLo + (size_t)e * 512 * 32,
                    nrm_pfc + e * 512, Bh, Bl, nd, c, kg, key2);
    knn_merge_lanes(key2);

    unsigned key1[8];
#pragma unroll
    for (int k = 0; k < 8; k++) key1[k] = 0xFFFFFFFFu;
    knn_scan<4>(svHi + (size_t)e * 64 * 32, svLo + (size_t)e * 64 * 32,
                nrm_sv + e * 64, Bh, Bl, nd, c, kg, key1);
    knn_merge_lanes(key1);

    // base (read BEFORE B3 overwrites these rows)
    const float* bp = f1base + trow * 32 + kg * 8;
    float4 bb0 = *(const float4*)(bp);
    float4 bb1 = *(const float4*)(bp + 4);
    float base[8] = {bb0.x, bb0.y, bb0.z, bb0.w, bb1.x, bb1.y, bb1.z, bb1.w};

    float m[8];
    // f2 = elu(base + max Y2[rows2]); keep split for B3
    gather_max8(Y2 + (size_t)e * 512 * 32, key2, kg, m);
    float v2[8];
    short8 Fh, Fl;
#pragma unroll
    for (int i = 0; i < 8; i++) {
        v2[i] = elu_f(base[i] + m[i]);
        short h, l;
        bfsplit(v2[i], h, l);
        Fh[i] = h; Fl[i] = l;
    }
    {
        float4* op = (float4*)(f2 + trow * 32 + kg * 8);
        op[0] = (float4){v2[0], v2[1], v2[2], v2[3]};
        op[1] = (float4){v2[4], v2[5], v2[6], v2[7]};
    }

    // f1 = elu(base + max Y1[rows1]) -> planes + norm (kept in regs)
    gather_max8(Y1 + (size_t)e * 64 * 32, key1, kg, m);
    float v1[8];
    float nr = 0.f;
    short8 Hh, Hl;
#pragma unroll
    for (int i = 0; i < 8; i++) {
        v1[i] = elu_f(base[i] + m[i]);
        nr = fmaf(v1[i], v1[i], nr);
        short h, l;
        bfsplit(v1[i], h, l);
        Hh[i] = h; Hl[i] = l;
    }
    nr += __shfl_xor(nr, 16);
    nr += __shfl_xor(nr, 32);
    if (kg == 0) nrm_f1[trow] = nr;
    *(short8*)(f1Hi + trow * 32 + kg * 8) = Hh;
    *(short8*)(f1Lo + trow * 32 + kg * 8) = Hl;

    // Y3 = f1 @ w2h (bias 0) for this wave's 16 dst rows (r7 yb3 order)
    f32x4 a0 = {0.f, 0.f, 0.f, 0.f}, a1 = {0.f, 0.f, 0.f, 0.f};
    a0 = __builtin_amdgcn_mfma_f32_16x16x32_bf16(Hl, WYh0, a0, 0, 0, 0);
    a0 = __builtin_amdgcn_mfma_f32_16x16x32_bf16(Hh, WYl0, a0, 0, 0, 0);
    a0 = __builtin_amdgcn_mfma_f32_16x16x32_bf16(Hh, WYh0, a0, 0, 0, 0);
    a1 = __builtin_amdgcn_mfma_f32_16x16x32_bf16(Hl, WYh1, a1, 0, 0, 0);
    a1 = __builtin_amdgcn_mfma_f32_16x16x32_bf16(Hh, WYl1, a1, 0, 0, 0);
    a1 = __builtin_amdgcn_mfma_f32_16x16x32_bf16(Hh, WYh1, a1, 0, 0, 0);
    // B3 = f2 @ wd + conv_b
    f32x4 q0 = {bd0, bd0, bd0, bd0}, q1 = {bd1, bd1, bd1, bd1};
    q0 = __builtin_amdgcn_mfma_f32_16x16x32_bf16(Fl, WDh0, q0, 0, 0, 0);
    q0 = __builtin_amdgcn_mfma_f32_16x16x32_bf16(Fh, WDl0, q0, 0, 0, 0);
    q0 = __builtin_amdgcn_mfma_f32_16x16x32_bf16(Fh, WDh0, q0, 0, 0, 0);
    q1 = __builtin_amdgcn_mfma_f32_16x16x32_bf16(Fl, WDh1, q1, 0, 0, 0);
    q1 = __builtin_amdgcn_mfma_f32_16x16x32_bf16(Fh, WDl1, q1, 0, 0, 0);
    q1 = __builtin_amdgcn_mfma_f32_16x16x32_bf16(Fh, WDh1, q1, 0, 0, 0);

    int drow = dstbase + kg * 4;
#pragma unroll
    for (int r = 0; r < 4; r++) {
        size_t off = ((size_t)e * 512 + drow + r) * 32 + c;
        Y3[off] = a0[r];  Y3[off + 16] = a1[r];
        B3[off] = q0[r];  B3[off + 16] = q1[r];
    }
}

// knn3 + g3 fused (r8/r10-validated): 2048 blocks
__global__ __launch_bounds__(256) void knn3_kernel(
    const unsigned short* __restrict__ f1Hi, const unsigned short* __restrict__ f1Lo,
    const float* __restrict__ nrm_f1,
    const float* __restrict__ f2,
    const float* __restrict__ Y3, const float* __restrict__ B3,
    float* __restrict__ pool)
{
    __shared__ float sp[4][32];
    int bid = blockIdx.x;
    int e = bid & 255, j = bid >> 8;
    int tid = threadIdx.x;
    int lane = tid & 63, wave = tid >> 6;
    int c = lane & 15, kg = lane >> 4;
    int dstbase = j * 64 + wave * 16;
    size_t trow = (size_t)e * 512 + dstbase + c;

    short8 Bh, Bl;
    float nd;
    knn_build_B(f2 + (size_t)e * 512 * 32, dstbase, c, kg, Bh, Bl, nd);

    unsigned key[8];
#pragma unroll
    for (int k = 0; k < 8; k++) key[k] = 0xFFFFFFFFu;
    knn_scan32_dual(f1Hi + (size_t)e * 512 * 32, f1Lo + (size_t)e * 512 * 32,
                    nrm_f1 + e * 512, Bh, Bl, nd, c, kg, key);
    knn_merge_lanes(key);

    float m[8];
    gather_max8(Y3 + (size_t)e * 512 * 32, key, kg, m);

    const float* bp = B3 + trow * 32 + kg * 8;
    float4 bb0 = *(const float4*)(bp);
    float4 bb1 = *(const float4*)(bp + 4);
    float base[8] = {bb0.x, bb0.y, bb0.z, bb0.w, bb1.x, bb1.y, bb1.z, bb1.w};

    float r[8];
#pragma unroll
    for (int i = 0; i < 8; i++) r[i] = elu_f(base[i] + m[i]);

#pragma unroll
    for (int off = 1; off < 16; off <<= 1) {
#pragma unroll
        for (int i = 0; i < 8; i++) r[i] += __shfl_xor(r[i], off);
    }
    if (c == 0) {
#pragma unroll
        for (int i = 0; i < 8; i++) sp[wave][kg * 8 + i] = r[i];
    }
    __syncthreads();
    if (tid < 32)
        pool[((size_t)e * 8 + j) * 32 + tid] =
            sp[0][tid] + sp[1][tid] + sp[2][tid] + sp[3][tid];
}

// final: 8 pooled partials per event + MLP + sigmoid + arange
__global__ __launch_bounds__(64) void final_kernel(
    const float* __restrict__ pool,
    const float* __restrict__ W1, const float* __restrict__ b1,
    const float* __restrict__ W2, const float* __restrict__ b2,
    float* __restrict__ outp)
{
    int b = blockIdx.x;
    int lane = threadIdx.x, c = lane & 31;
    __shared__ float sp[32];
    __shared__ float sh1[32];
    if (lane < 32) {
        float s = 0.f;
#pragma unroll
        for (int jj = 0; jj < 8; jj++)
            s += pool[((size_t)b * 8 + jj) * 32 + c];
        sp[c] = s * (1.0f / 512.0f);
    }
    __syncthreads();
    if (lane < 32) {
        float h = b1[c];
#pragma unroll
        for (int d = 0; d < 32; d++) h = fmaf(sp[d], W1[d * 32 + c], h);
        sh1[c] = elu_f(h);
    }
    __syncthreads();
    if (lane == 0) {
        float o = b2[0];
#pragma unroll
        for (int d = 0; d < 32; d++) o = fmaf(sh1[d], W2[d], o);
        o = 1.f / (1.f + __expf(-o));
        outp[b] = o;
        outp[NB + b] = (float)b;
    }
}

extern "C" void kernel_launch(void* const* d_in, const int* in_sizes, int n_in,
                              void* d_out, int out_size, void* d_ws, size_t ws_size,
                              hipStream_t stream) {
    const float* x_sv  = (const float*)d_in[0];
    const float* x_trk = (const float*)d_in[1];
    const float* x_pfc = (const float*)d_in[2];
    const float* sv_W1  = (const float*)d_in[6];
    const float* sv_b1  = (const float*)d_in[7];
    const float* sv_W2  = (const float*)d_in[8];
    const float* sv_b2  = (const float*)d_in[9];
    const float* trk_W1 = (const float*)d_in[10];
    const float* trk_b1 = (const float*)d_in[11];
    const float* trk_W2 = (const float*)d_in[12];
    const float* trk_b2 = (const float*)d_in[13];
    const float* pfc_W1 = (const float*)d_in[14];
    const float* pfc_b1 = (const float*)d_in[15];
    const float* pfc_W2 = (const float*)d_in[16];
    const float* pfc_b2 = (const float*)d_in[17];
    const float* conv_W = (const float*)d_in[18];
    const float* conv_b = (const float*)d_in[19];
    const float* out_W1 = (const float*)d_in[20];
    const float* out_b1 = (const float*)d_in[21];
    const float* out_W2 = (const float*)d_in[22];
    const float* out_b2 = (const float*)d_in[23];

    float* ws = (float*)d_ws;
    const size_t SV_E  = (size_t)NB * 64 * 32;     //   524288
    const size_t TRK_E = (size_t)NB * 512 * 32;    //  4194304
    float* f1base  = ws;                           // B3 aliases (in knn12)
    float* f2      = f1base + TRK_E;
    float* trk_enc = f2 + TRK_E;                   // Y3 aliases (in knn12)
    float* Y1      = trk_enc + TRK_E;
    float* Y2      = Y1 + SV_E;
    unsigned short* svHi  = (unsigned short*)(Y2 + TRK_E);   // SV_E u16
    unsigned short* svLo  = svHi + SV_E;                     // pool aliases
    unsigned short* pfcHi = svLo + SV_E;                     // TRK_E u16
    unsigned short* pfcLo = pfcHi + TRK_E;
    unsigned short* f1Hi  = pfcLo + TRK_E;
    unsigned short* f1Lo  = f1Hi + TRK_E;
    float* nrm_sv  = (float*)(f1Lo + TRK_E);                 // NB*64
    float* nrm_pfc = nrm_sv + (size_t)NB * 64;               // NB*512
    float* nrm_f1  = nrm_pfc + (size_t)NB * 512;             // NB*512
    float* Y3   = trk_enc;          // each wave reads-then-writes own rows
    float* B3   = f1base;           // same argument
    float* pool = (float*)svHi;     // sv planes dead after knn12; NB*8*32 f32

    encode_all_kernel<<<1088, 256, 0, stream>>>(
        x_sv, x_trk, x_pfc,
        sv_W1, sv_b1, sv_W2, sv_b2,
        trk_W1, trk_b1, trk_W2, trk_b2,
        pfc_W1, pfc_b1, pfc_W2, pfc_b2,
        conv_W, conv_b,
        trk_enc, Y1, Y2, f1base,
        svHi, svLo, nrm_sv, pfcHi, pfcLo, nrm_pfc);

    knn12_kernel<<<2048, 256, 0, stream>>>(svHi, svLo, nrm_sv,
                                           pfcHi, pfcLo, nrm_pfc,
                                           trk_enc, Y1, Y2,
                                           f1base, f2, f1Hi, f1Lo, nrm_f1,
                                           Y3, B3, conv_W, conv_b);

    knn3_kernel<<<2048, 256, 0, stream>>>(f1Hi, f1Lo, nrm_f1, f2, Y3, B3, pool);

    final_kernel<<<NB, 64, 0, stream>>>(pool, out_W1, out_b1, out_W2, out_b2, (float*)d_out);
}

// Round 13
// 275.331 us; speedup vs baseline: 1.7348x; 1.0772x over previous
//
#include <hip/hip_runtime.h>
#include <math.h>

#define NB 256      // events
#define KNN 8

typedef __attribute__((ext_vector_type(8))) short short8;
typedef __attribute__((ext_vector_type(4))) float f32x4;

__device__ __forceinline__ float elu_f(float x) {
    return x > 0.f ? x : __expf(x) - 1.f;
}

// round-to-nearest-even fp32 -> bf16 (returns low 16 bits)
__device__ __forceinline__ unsigned bf16rn(float x) {
    unsigned u = __float_as_uint(x);
    return (u + 0x7FFFu + ((u >> 16) & 1u)) >> 16;
}

// split fp32 -> (hi, lo) bf16 pair
__device__ __forceinline__ void bfsplit(float x, short& h, short& l) {
    unsigned hu = bf16rn(x);
    h = (short)hu;
    l = (short)bf16rn(x - __uint_as_float(hu << 16));
}

// ---- sorting-network primitives on u32 keys (validated r1-r12) ------------
__device__ __forceinline__ void cex(unsigned& a, unsigned& b) {
    unsigned lo = min(a, b), hi = max(a, b);
    a = lo; b = hi;
}

__device__ __forceinline__ void sort8(unsigned* s) {
    cex(s[0], s[1]); cex(s[2], s[3]); cex(s[4], s[5]); cex(s[6], s[7]);
    cex(s[0], s[2]); cex(s[1], s[3]); cex(s[4], s[6]); cex(s[5], s[7]);
    cex(s[1], s[2]); cex(s[5], s[6]);
    cex(s[0], s[4]); cex(s[1], s[5]); cex(s[2], s[6]); cex(s[3], s[7]);
    cex(s[2], s[4]); cex(s[3], s[5]);
    cex(s[1], s[2]); cex(s[3], s[4]); cex(s[5], s[6]);
}

__device__ __forceinline__ void merge8(unsigned* v, const unsigned* s) {
#pragma unroll
    for (int i = 0; i < 8; i++) v[i] = min(v[i], s[7 - i]);
    cex(v[0], v[4]); cex(v[1], v[5]); cex(v[2], v[6]); cex(v[3], v[7]);
    cex(v[0], v[2]); cex(v[1], v[3]); cex(v[4], v[6]); cex(v[5], v[7]);
    cex(v[0], v[1]); cex(v[2], v[3]); cex(v[4], v[5]); cex(v[6], v[7]);
}

// ================= MFMA encoder (r6-validated math; 128 nodes/block) =======
// Wave owns 32 rows (2 row-tiles of 16); 16 KB LDS -> higher occupancy.
template<int FIN, int MODE>
__device__ void encode_mfma_body(const float* __restrict__ x,
    const float* __restrict__ W1, const float* __restrict__ b1,
    const float* __restrict__ W2, const float* __restrict__ b2,
    const float* __restrict__ conv_W, const float* __restrict__ conv_b,
    float* __restrict__ enc, float* __restrict__ e1,
    unsigned short* __restrict__ hiP, unsigned short* __restrict__ loP,
    float* __restrict__ nrmP,
    int blk, float* __restrict__ sx)
{
    int tid = threadIdx.x;
    int lane = tid & 63, wv = tid >> 6;
    int c = lane & 15, kg = lane >> 4;
    size_t node0 = (size_t)blk * 128;

    {
        const float* xb = x + node0 * FIN;
        for (int i = tid; i < 4096; i += 256) {
            int n = i >> 5, f = i & 31;
            sx[i] = (f < FIN) ? xb[n * FIN + f] : 0.f;
        }
    }
    __syncthreads();

    int rb = wv * 32;   // wave-private rows [rb, rb+32)

#pragma unroll
    for (int ph = 0; ph < 3; ph++) {
        short8 Bh0, Bl0, Bh1, Bl1;
#pragma unroll
        for (int e = 0; e < 8; e++) {
            int kk = kg * 8 + e;
            float w0, w1;
            if (ph == 0) {
                w0 = (kk < FIN) ? W1[kk * 32 + c] : 0.f;
                w1 = (kk < FIN) ? W1[kk * 32 + 16 + c] : 0.f;
            } else if (ph == 1) {
                w0 = W2[kk * 32 + c];
                w1 = W2[kk * 32 + 16 + c];
            } else {
                w0 = conv_W[1024 + kk * 32 + c];
                w1 = conv_W[1024 + kk * 32 + 16 + c];
                if (MODE == 1) {
                    w0 = conv_W[kk * 32 + c] - w0;
                    w1 = conv_W[kk * 32 + 16 + c] - w1;
                }
            }
            short h, l;
            bfsplit(w0, h, l); Bh0[e] = h; Bl0[e] = l;
            bfsplit(w1, h, l); Bh1[e] = h; Bl1[e] = l;
        }
        float bias0, bias1;
        if (ph == 0)      { bias0 = b1[c]; bias1 = b1[16 + c]; }
        else if (ph == 1) { bias0 = b2[c]; bias1 = b2[16 + c]; }
        else              { bias0 = (MODE == 1) ? conv_b[c] : 0.f;
                            bias1 = (MODE == 1) ? conv_b[16 + c] : 0.f; }

#pragma unroll
        for (int t = 0; t < 2; t++) {
            int tb = rb + t * 16;
            int arow = tb + c;
            const float* ap = sx + arow * 32 + kg * 8;
            float4 a0 = *(const float4*)(ap);
            float4 a1 = *(const float4*)(ap + 4);
            float av[8] = {a0.x, a0.y, a0.z, a0.w, a1.x, a1.y, a1.z, a1.w};
            short8 Ah, Al;
#pragma unroll
            for (int e = 0; e < 8; e++) {
                short h, l;
                bfsplit(av[e], h, l);
                Ah[e] = h; Al[e] = l;
            }

            if (MODE == 0 && ph == 2) {
                float nr = 0.f;
#pragma unroll
                for (int e = 0; e < 8; e++) nr = fmaf(av[e], av[e], nr);
                nr += __shfl_xor(nr, 16);
                nr += __shfl_xor(nr, 32);
                if (kg == 0) nrmP[node0 + arow] = nr;
                *(short8*)(hiP + (node0 + arow) * 32 + kg * 8) = Ah;
                *(short8*)(loP + (node0 + arow) * 32 + kg * 8) = Al;
            }

            f32x4 acc0 = {bias0, bias0, bias0, bias0};
            f32x4 acc1 = {bias1, bias1, bias1, bias1};
            acc0 = __builtin_amdgcn_mfma_f32_16x16x32_bf16(Al, Bh0, acc0, 0, 0, 0);
            acc0 = __builtin_amdgcn_mfma_f32_16x16x32_bf16(Ah, Bl0, acc0, 0, 0, 0);
            acc0 = __builtin_amdgcn_mfma_f32_16x16x32_bf16(Ah, Bh0, acc0, 0, 0, 0);
            acc1 = __builtin_amdgcn_mfma_f32_16x16x32_bf16(Al, Bh1, acc1, 0, 0, 0);
            acc1 = __builtin_amdgcn_mfma_f32_16x16x32_bf16(Ah, Bl1, acc1, 0, 0, 0);
            acc1 = __builtin_amdgcn_mfma_f32_16x16x32_bf16(Ah, Bh1, acc1, 0, 0, 0);

            int drow = tb + kg * 4;
            if (ph < 2) {
#pragma unroll
                for (int r = 0; r < 4; r++) {
                    float v0 = elu_f(acc0[r]);
                    float v1 = elu_f(acc1[r]);
                    sx[(drow + r) * 32 + c] = v0;
                    sx[(drow + r) * 32 + 16 + c] = v1;
                    if (MODE == 1 && ph == 1) {
                        size_t off = (node0 + drow + r) * 32 + c;
                        enc[off] = v0;
                        enc[off + 16] = v1;
                    }
                }
            } else {
#pragma unroll
                for (int r = 0; r < 4; r++) {
                    size_t off = (node0 + drow + r) * 32 + c;
                    e1[off] = acc0[r];
                    e1[off + 16] = acc1[r];
                }
            }
        }
    }
}

// 2176 blocks: sv(128) | trk(1024) | pfc(1024); 128 nodes/block
__global__ __launch_bounds__(256) void encode_all_kernel(
    const float* __restrict__ x_sv, const float* __restrict__ x_trk, const float* __restrict__ x_pfc,
    const float* __restrict__ sv_W1, const float* __restrict__ sv_b1,
    const float* __restrict__ sv_W2, const float* __restrict__ sv_b2,
    const float* __restrict__ trk_W1, const float* __restrict__ trk_b1,
    const float* __restrict__ trk_W2, const float* __restrict__ trk_b2,
    const float* __restrict__ pfc_W1, const float* __restrict__ pfc_b1,
    const float* __restrict__ pfc_W2, const float* __restrict__ pfc_b2,
    const float* __restrict__ conv_W, const float* __restrict__ conv_b,
    float* __restrict__ trk_enc,
    float* __restrict__ Y1, float* __restrict__ Y2,
    float* __restrict__ f1base,
    unsigned short* __restrict__ svHi, unsigned short* __restrict__ svLo, float* __restrict__ nrm_sv,
    unsigned short* __restrict__ pfcHi, unsigned short* __restrict__ pfcLo, float* __restrict__ nrm_pfc)
{
    __shared__ float sx[4096];
    int bid = blockIdx.x;
    if (bid < 128)
        encode_mfma_body<14, 0>(x_sv, sv_W1, sv_b1, sv_W2, sv_b2, conv_W, conv_b,
                                nullptr, Y1, svHi, svLo, nrm_sv, bid, sx);
    else if (bid < 1152)
        encode_mfma_body<30, 1>(x_trk, trk_W1, trk_b1, trk_W2, trk_b2, conv_W, conv_b,
                                trk_enc, f1base, nullptr, nullptr, nullptr, bid - 128, sx);
    else
        encode_mfma_body<10, 0>(x_pfc, pfc_W1, pfc_b1, pfc_W2, pfc_b2, conv_W, conv_b,
                                nullptr, Y2, pfcHi, pfcLo, nrm_pfc, bid - 1152, sx);
}

// ================= kNN via MFMA Gram tiles (r4/r7/r8/r10-validated) ========
__device__ __forceinline__ void knn_build_B(const float* __restrict__ dstF,
                                            int dstbase, int c, int kg,
                                            short8& Bh, short8& Bl, float& nd)
{
    const float* brow = dstF + (size_t)(dstbase + c) * 32 + kg * 8;
    float4 b0 = *(const float4*)(brow);
    float4 b1 = *(const float4*)(brow + 4);
    float bx[8] = {b0.x, b0.y, b0.z, b0.w, b1.x, b1.y, b1.z, b1.w};
    nd = 0.f;
#pragma unroll
    for (int i = 0; i < 8; i++) {
        float xv = bx[i];
        nd = fmaf(xv, xv, nd);
        short h, l;
        bfsplit(xv, h, l);
        Bh[i] = h; Bl[i] = l;
    }
    nd += __shfl_xor(nd, 16);
    nd += __shfl_xor(nd, 32);
}

// candidate batch over tiles (t0, t0+1) -> 8 keys
__device__ __forceinline__ void knn_batch(
    const unsigned short* __restrict__ srcHi, const unsigned short* __restrict__ srcLo,
    const float* __restrict__ snrm,
    short8 Bh, short8 Bl, float nd, int c, int kg, int t0,
    unsigned* cand)
{
#pragma unroll
    for (int u = 0; u < 2; u++) {
        int tt = t0 + u;
        size_t arow = ((size_t)(tt * 16 + c)) * 32 + (size_t)kg * 8;
        short8 Ah = *(const short8*)(srcHi + arow);
        short8 Al = *(const short8*)(srcLo + arow);
        f32x4 acc = {0.f, 0.f, 0.f, 0.f};
        acc = __builtin_amdgcn_mfma_f32_16x16x32_bf16(Al, Bl, acc, 0, 0, 0);
        acc = __builtin_amdgcn_mfma_f32_16x16x32_bf16(Al, Bh, acc, 0, 0, 0);
        acc = __builtin_amdgcn_mfma_f32_16x16x32_bf16(Ah, Bl, acc, 0, 0, 0);
        acc = __builtin_amdgcn_mfma_f32_16x16x32_bf16(Ah, Bh, acc, 0, 0, 0);
        float4 sn = *(const float4*)(snrm + tt * 16 + kg * 4);
        int sb = tt * 16 + kg * 4;
        cand[u*4+0] = (__float_as_uint(fmaf(-2.f, acc[0], sn.x + nd)) & 0xFFFFFE00u) | (unsigned)(sb + 0);
        cand[u*4+1] = (__float_as_uint(fmaf(-2.f, acc[1], sn.y + nd)) & 0xFFFFFE00u) | (unsigned)(sb + 1);
        cand[u*4+2] = (__float_as_uint(fmaf(-2.f, acc[2], sn.z + nd)) & 0xFFFFFE00u) | (unsigned)(sb + 2);
        cand[u*4+3] = (__float_as_uint(fmaf(-2.f, acc[3], sn.w + nd)) & 0xFFFFFE00u) | (unsigned)(sb + 3);
    }
}

// single-chain scan (short src sets, NT even)
template<int NT>
__device__ __forceinline__ void knn_scan(
    const unsigned short* __restrict__ srcHi, const unsigned short* __restrict__ srcLo,
    const float* __restrict__ snrm,
    short8 Bh, short8 Bl, float nd, int c, int kg,
    unsigned* key)
{
    for (int t = 0; t < NT; t += 2) {
        unsigned cand[8];
        knn_batch(srcHi, srcLo, snrm, Bh, Bl, nd, c, kg, t, cand);
        sort8(cand);
        merge8(key, cand);
    }
}

// dual-chain 32-tile scan (r12-validated, bit-identical to sequential)
__device__ __forceinline__ void knn_scan32_dual(
    const unsigned short* __restrict__ srcHi, const unsigned short* __restrict__ srcLo,
    const float* __restrict__ snrm,
    short8 Bh, short8 Bl, float nd, int c, int kg,
    unsigned* key)
{
    unsigned keyB[8];
#pragma unroll
    for (int k = 0; k < 8; k++) keyB[k] = 0xFFFFFFFFu;
    for (int t = 0; t < 16; t += 2) {
        unsigned ca[8], cb[8];
        knn_batch(srcHi, srcLo, snrm, Bh, Bl, nd, c, kg, t, ca);
        knn_batch(srcHi, srcLo, snrm, Bh, Bl, nd, c, kg, 16 + t, cb);
        sort8(ca); merge8(key, ca);
        sort8(cb); merge8(keyB, cb);
    }
    merge8(key, keyB);
}

// after symmetric merges all 4 lanes of a dst column hold the identical
// final sorted top-8 (keys unique -> deterministic).
__device__ __forceinline__ void knn_merge_lanes(unsigned* key)
{
    unsigned oth[8];
#pragma unroll
    for (int k = 0; k < 8; k++) oth[k] = __shfl_xor(key[k], 16);
    merge8(key, oth);
#pragma unroll
    for (int k = 0; k < 8; k++) oth[k] = __shfl_xor(key[k], 32);
    merge8(key, oth);
}

__device__ __forceinline__ void gather_max8(const float* __restrict__ Yb,
                                            const unsigned* key, int kg, float* m)
{
    const float* r0 = Yb + (size_t)(key[0] & 511u) * 32 + kg * 8;
    float4 a = *(const float4*)(r0);
    float4 b = *(const float4*)(r0 + 4);
    m[0] = a.x; m[1] = a.y; m[2] = a.z; m[3] = a.w;
    m[4] = b.x; m[5] = b.y; m[6] = b.z; m[7] = b.w;
#pragma unroll
    for (int k = 1; k < 8; k++) {
        const float* rr = Yb + (size_t)(key[k] & 511u) * 32 + kg * 8;
        float4 va = *(const float4*)(rr);
        float4 vb = *(const float4*)(rr + 4);
        m[0] = fmaxf(m[0], va.x); m[1] = fmaxf(m[1], va.y);
        m[2] = fmaxf(m[2], va.z); m[3] = fmaxf(m[3], va.w);
        m[4] = fmaxf(m[4], vb.x); m[5] = fmaxf(m[5], vb.y);
        m[6] = fmaxf(m[6], vb.z); m[7] = fmaxf(m[7], vb.w);
    }
}

// knn12 + g12 + yb3 fused: 2048 blocks (r10-validated aliasing). Conv-W
// fragment build MOVED to after the scans (sched_barrier-pinned) so its 32
// VGPRs are not live across the scan -> higher occupancy.
__global__ __launch_bounds__(256) void knn12_kernel(
    const unsigned short* __restrict__ svHi, const unsigned short* __restrict__ svLo,
    const float* __restrict__ nrm_sv,
    const unsigned short* __restrict__ pfcHi, const unsigned short* __restrict__ pfcLo,
    const float* __restrict__ nrm_pfc,
    const float* __restrict__ trk_enc,
    const float* __restrict__ Y1, const float* __restrict__ Y2,
    const float* __restrict__ f1base, float* __restrict__ f2,
    unsigned short* __restrict__ f1Hi, unsigned short* __restrict__ f1Lo,
    float* __restrict__ nrm_f1,
    float* __restrict__ Y3, float* __restrict__ B3,
    const float* __restrict__ conv_W, const float* __restrict__ conv_b)
{
    int bid = blockIdx.x;
    int e = bid & 255, j = bid >> 8;
    int tid = threadIdx.x;
    int lane = tid & 63, wave = tid >> 6;
    int c = lane & 15, kg = lane >> 4;
    int dstbase = j * 64 + wave * 16;
    size_t trow = (size_t)e * 512 + dstbase + c;

    short8 Bh, Bl;
    float nd;
    knn_build_B(trk_enc + (size_t)e * 512 * 32, dstbase, c, kg, Bh, Bl, nd);

    unsigned key2[8];
#pragma unroll
    for (int k = 0; k < 8; k++) key2[k] = 0xFFFFFFFFu;
    knn_scan32_dual(pfcHi + (size_t)e * 512 * 32, pfcLo + (size_t)e * 512 * 32,
                    nrm_pfc + e * 512, Bh, Bl, nd, c, kg, key2);
    knn_merge_lanes(key2);

    unsigned key1[8];
#pragma unroll
    for (int k = 0; k < 8; k++) key1[k] = 0xFFFFFFFFu;
    knn_scan<4>(svHi + (size_t)e * 64 * 32, svLo + (size_t)e * 64 * 32,
                nrm_sv + e * 64, Bh, Bl, nd, c, kg, key1);
    knn_merge_lanes(key1);

    // base (read BEFORE B3 overwrites these rows)
    const float* bp = f1base + trow * 32 + kg * 8;
    float4 bb0 = *(const float4*)(bp);
    float4 bb1 = *(const float4*)(bp + 4);
    float base[8] = {bb0.x, bb0.y, bb0.z, bb0.w, bb1.x, bb1.y, bb1.z, bb1.w};

    float m[8];
    // f2 = elu(base + max Y2[rows2]); keep split for B3
    gather_max8(Y2 + (size_t)e * 512 * 32, key2, kg, m);
    float v2[8];
    short8 Fh, Fl;
#pragma unroll
    for (int i = 0; i < 8; i++) {
        v2[i] = elu_f(base[i] + m[i]);
        short h, l;
        bfsplit(v2[i], h, l);
        Fh[i] = h; Fl[i] = l;
    }
    {
        float4* op = (float4*)(f2 + trow * 32 + kg * 8);
        op[0] = (float4){v2[0], v2[1], v2[2], v2[3]};
        op[1] = (float4){v2[4], v2[5], v2[6], v2[7]};
    }

    // f1 = elu(base + max Y1[rows1]) -> planes + norm (kept in regs)
    gather_max8(Y1 + (size_t)e * 64 * 32, key1, kg, m);
    float v1[8];
    float nr = 0.f;
    short8 Hh, Hl;
#pragma unroll
    for (int i = 0; i < 8; i++) {
        v1[i] = elu_f(base[i] + m[i]);
        nr = fmaf(v1[i], v1[i], nr);
        short h, l;
        bfsplit(v1[i], h, l);
        Hh[i] = h; Hl[i] = l;
    }
    nr += __shfl_xor(nr, 16);
    nr += __shfl_xor(nr, 32);
    if (kg == 0) nrm_f1[trow] = nr;
    *(short8*)(f1Hi + trow * 32 + kg * 8) = Hh;
    *(short8*)(f1Lo + trow * 32 + kg * 8) = Hl;

    // ---- conv-W fragments built HERE (not at kernel start) ---------------
    __builtin_amdgcn_sched_barrier(0);   // do not hoist the loads upward
    short8 WYh0, WYl0, WYh1, WYl1, WDh0, WDl0, WDh1, WDl1;
#pragma unroll
    for (int ee = 0; ee < 8; ee++) {
        int kk = kg * 8 + ee;
        float y0 = conv_W[1024 + kk * 32 + c];
        float y1 = conv_W[1024 + kk * 32 + 16 + c];
        float d0 = conv_W[kk * 32 + c] - y0;
        float d1 = conv_W[kk * 32 + 16 + c] - y1;
        short h, l;
        bfsplit(y0, h, l); WYh0[ee] = h; WYl0[ee] = l;
        bfsplit(y1, h, l); WYh1[ee] = h; WYl1[ee] = l;
        bfsplit(d0, h, l); WDh0[ee] = h; WDl0[ee] = l;
        bfsplit(d1, h, l); WDh1[ee] = h; WDl1[ee] = l;
    }
    float bd0 = conv_b[c], bd1 = conv_b[16 + c];

    // Y3 = f1 @ w2h (bias 0) for this wave's 16 dst rows (r7 yb3 order)
    f32x4 a0 = {0.f, 0.f, 0.f, 0.f}, a1 = {0.f, 0.f, 0.f, 0.f};
    a0 = __builtin_amdgcn_mfma_f32_16x16x32_bf16(Hl, WYh0, a0, 0, 0, 0);
    a0 = __builtin_amdgcn_mfma_f32_16x16x32_bf16(Hh, WYl0, a0, 0, 0, 0);
    a0 = __builtin_amdgcn_mfma_f32_16x16x32_bf16(Hh, WYh0, a0, 0, 0, 0);
    a1 = __builtin_amdgcn_mfma_f32_16x16x32_bf16(Hl, WYh1, a1, 0, 0, 0);
    a1 = __builtin_amdgcn_mfma_f32_16x16x32_bf16(Hh, WYl1, a1, 0, 0, 0);
    a1 = __builtin_amdgcn_mfma_f32_16x16x32_bf16(Hh, WYh1, a1, 0, 0, 0);
    // B3 = f2 @ wd + conv_b
    f32x4 q0 = {bd0, bd0, bd0, bd0}, q1 = {bd1, bd1, bd1, bd1};
    q0 = __builtin_amdgcn_mfma_f32_16x16x32_bf16(Fl, WDh0, q0, 0, 0, 0);
    q0 = __builtin_amdgcn_mfma_f32_16x16x32_bf16(Fh, WDl0, q0, 0, 0, 0);
    q0 = __builtin_amdgcn_mfma_f32_16x16x32_bf16(Fh, WDh0, q0, 0, 0, 0);
    q1 = __builtin_amdgcn_mfma_f32_16x16x32_bf16(Fl, WDh1, q1, 0, 0, 0);
    q1 = __builtin_amdgcn_mfma_f32_16x16x32_bf16(Fh, WDl1, q1, 0, 0, 0);
    q1 = __builtin_amdgcn_mfma_f32_16x16x32_bf16(Fh, WDh1, q1, 0, 0, 0);

    int drow = dstbase + kg * 4;
#pragma unroll
    for (int r = 0; r < 4; r++) {
        size_t off = ((size_t)e * 512 + drow + r) * 32 + c;
        Y3[off] = a0[r];  Y3[off + 16] = a1[r];
        B3[off] = q0[r];  B3[off + 16] = q1[r];
    }
}

// knn3 + g3 fused (r8/r10-validated): 2048 blocks
__global__ __launch_bounds__(256) void knn3_kernel(
    const unsigned short* __restrict__ f1Hi, const unsigned short* __restrict__ f1Lo,
    const float* __restrict__ nrm_f1,
    const float* __restrict__ f2,
    const float* __restrict__ Y3, const float* __restrict__ B3,
    float* __restrict__ pool)
{
    __shared__ float sp[4][32];
    int bid = blockIdx.x;
    int e = bid & 255, j = bid >> 8;
    int tid = threadIdx.x;
    int lane = tid & 63, wave = tid >> 6;
    int c = lane & 15, kg = lane >> 4;
    int dstbase = j * 64 + wave * 16;
    size_t trow = (size_t)e * 512 + dstbase + c;

    short8 Bh, Bl;
    float nd;
    knn_build_B(f2 + (size_t)e * 512 * 32, dstbase, c, kg, Bh, Bl, nd);

    unsigned key[8];
#pragma unroll
    for (int k = 0; k < 8; k++) key[k] = 0xFFFFFFFFu;
    knn_scan32_dual(f1Hi + (size_t)e * 512 * 32, f1Lo + (size_t)e * 512 * 32,
                    nrm_f1 + e * 512, Bh, Bl, nd, c, kg, key);
    knn_merge_lanes(key);

    float m[8];
    gather_max8(Y3 + (size_t)e * 512 * 32, key, kg, m);

    const float* bp = B3 + trow * 32 + kg * 8;
    float4 bb0 = *(const float4*)(bp);
    float4 bb1 = *(const float4*)(bp + 4);
    float base[8] = {bb0.x, bb0.y, bb0.z, bb0.w, bb1.x, bb1.y, bb1.z, bb1.w};

    float r[8];
#pragma unroll
    for (int i = 0; i < 8; i++) r[i] = elu_f(base[i] + m[i]);

#pragma unroll
    for (int off = 1; off < 16; off <<= 1) {
#pragma unroll
        for (int i = 0; i < 8; i++) r[i] += __shfl_xor(r[i], off);
    }
    if (c == 0) {
#pragma unroll
        for (int i = 0; i < 8; i++) sp[wave][kg * 8 + i] = r[i];
    }
    __syncthreads();
    if (tid < 32)
        pool[((size_t)e * 8 + j) * 32 + tid] =
            sp[0][tid] + sp[1][tid] + sp[2][tid] + sp[3][tid];
}

// final: 8 pooled partials per event + MLP + sigmoid + arange
__global__ __launch_bounds__(64) void final_kernel(
    const float* __restrict__ pool,
    const float* __restrict__ W1, const float* __restrict__ b1,
    const float* __restrict__ W2, const float* __restrict__ b2,
    float* __restrict__ outp)
{
    int b = blockIdx.x;
    int lane = threadIdx.x, c = lane & 31;
    __shared__ float sp[32];
    __shared__ float sh1[32];
    if (lane < 32) {
        float s = 0.f;
#pragma unroll
        for (int jj = 0; jj < 8; jj++)
            s += pool[((size_t)b * 8 + jj) * 32 + c];
        sp[c] = s * (1.0f / 512.0f);
    }
    __syncthreads();
    if (lane < 32) {
        float h = b1[c];
#pragma unroll
        for (int d = 0; d < 32; d++) h = fmaf(sp[d], W1[d * 32 + c], h);
        sh1[c] = elu_f(h);
    }
    __syncthreads();
    if (lane == 0) {
        float o = b2[0];
#pragma unroll
        for (int d = 0; d < 32; d++) o = fmaf(sh1[d], W2[d], o);
        o = 1.f / (1.f + __expf(-o));
        outp[b] = o;
        outp[NB + b] = (float)b;
    }
}

extern "C" void kernel_launch(void* const* d_in, const int* in_sizes, int n_in,
                              void* d_out, int out_size, void* d_ws, size_t ws_size,
                              hipStream_t stream) {
    const float* x_sv  = (const float*)d_in[0];
    const float* x_trk = (const float*)d_in[1];
    const float* x_pfc = (const float*)d_in[2];
    const float* sv_W1  = (const float*)d_in[6];
    const float* sv_b1  = (const float*)d_in[7];
    const float* sv_W2  = (const float*)d_in[8];
    const float* sv_b2  = (const float*)d_in[9];
    const float* trk_W1 = (const float*)d_in[10];
    const float* trk_b1 = (const float*)d_in[11];
    const float* trk_W2 = (const float*)d_in[12];
    const float* trk_b2 = (const float*)d_in[13];
    const float* pfc_W1 = (const float*)d_in[14];
    const float* pfc_b1 = (const float*)d_in[15];
    const float* pfc_W2 = (const float*)d_in[16];
    const float* pfc_b2 = (const float*)d_in[17];
    const float* conv_W = (const float*)d_in[18];
    const float* conv_b = (const float*)d_in[19];
    const float* out_W1 = (const float*)d_in[20];
    const float* out_b1 = (const float*)d_in[21];
    const float* out_W2 = (const float*)d_in[22];
    const float* out_b2 = (const float*)d_in[23];

    float* ws = (float*)d_ws;
    const size_t SV_E  = (size_t)NB * 64 * 32;     //   524288
    const size_t TRK_E = (size_t)NB * 512 * 32;    //  4194304
    float* f1base  = ws;                           // B3 aliases (in knn12)
    float* f2      = f1base + TRK_E;
    float* trk_enc = f2 + TRK_E;                   // Y3 aliases (in knn12)
    float* Y1      = trk_enc + TRK_E;
    float* Y2      = Y1 + SV_E;
    unsigned short* svHi  = (unsigned short*)(Y2 + TRK_E);   // SV_E u16
    unsigned short* svLo  = svHi + SV_E;                     // pool aliases
    unsigned short* pfcHi = svLo + SV_E;                     // TRK_E u16
    unsigned short* pfcLo = pfcHi + TRK_E;
    unsigned short* f1Hi  = pfcLo + TRK_E;
    unsigned short* f1Lo  = f1Hi + TRK_E;
    float* nrm_sv  = (float*)(f1Lo + TRK_E);                 // NB*64
    float* nrm_pfc = nrm_sv + (size_t)NB * 64;               // NB*512
    float* nrm_f1  = nrm_pfc + (size_t)NB * 512;             // NB*512
    float* Y3   = trk_enc;          // each wave reads-then-writes own rows
    float* B3   = f1base;           // same argument
    float* pool = (float*)svHi;     // sv planes dead after knn12; NB*8*32 f32

    encode_all_kernel<<<2176, 256, 0, stream>>>(
        x_sv, x_trk, x_pfc,
        sv_W1, sv_b1, sv_W2, sv_b2,
        trk_W1, trk_b1, trk_W2, trk_b2,
        pfc_W1, pfc_b1, pfc_W2, pfc_b2,
        conv_W, conv_b,
        trk_enc, Y1, Y2, f1base,
        svHi, svLo, nrm_sv, pfcHi, pfcLo, nrm_pfc);

    knn12_kernel<<<2048, 256, 0, stream>>>(svHi, svLo, nrm_sv,
                                           pfcHi, pfcLo, nrm_pfc,
                                           trk_enc, Y1, Y2,
                                           f1base, f2, f1Hi, f1Lo, nrm_f1,
                                           Y3, B3, conv_W, conv_b);

    knn3_kernel<<<2048, 256, 0, stream>>>(f1Hi, f1Lo, nrm_f1, f2, Y3, B3, pool);

    final_kernel<<<NB, 64, 0, stream>>>(pool, out_W1, out_b1, out_W2, out_b2, (float*)d_out);
}